// Round 5
// baseline (318.810 us; speedup 1.0000x reference)
//
#include <hip/hip_runtime.h>
#include <stdint.h>

#define M_TOT 16384      // B*S = 4*4096
#define K_DIM 2048
#define N_DIM 2048
#define W_ELEMS (N_DIM * K_DIM)   // 4194304

typedef int v4i  __attribute__((ext_vector_type(4)));
typedef int v16i __attribute__((ext_vector_type(16)));

// ---------------- async global -> LDS, 16B per lane ----------------
__device__ __forceinline__ void async_load16(const void* gptr, void* lptr) {
    __builtin_amdgcn_global_load_lds(
        (__attribute__((address_space(1))) void*)(uintptr_t)gptr,
        (__attribute__((address_space(3))) void*)(uint32_t)(uintptr_t)lptr,
        16, 0, 0);
}

__device__ __forceinline__ int qclamp(float v, int lo, int hi) {
    int q = (int)rintf(v);
    q = q > hi ? hi : (q < lo ? lo : q);
    return q & 255;
}

// ---------------- K1: per-block weight sum partials ----------------
__global__ __launch_bounds__(256) void wsum_kernel(const float* __restrict__ w,
                                                   double* __restrict__ spart) {
    int tid = blockIdx.x * 256 + threadIdx.x;
    const float4* w4 = (const float4*)w;
    double s = 0.0;
    #pragma unroll
    for (int it = 0; it < 8; it++) {               // 512*256*8 float4 = W_ELEMS/4 exact
        float4 v = w4[tid + it * 131072];
        s += (double)v.x + (double)v.y + (double)v.z + (double)v.w;
    }
    #pragma unroll
    for (int off = 32; off; off >>= 1) s += __shfl_down(s, off);
    __shared__ double ls[4];
    if ((threadIdx.x & 63) == 0) ls[threadIdx.x >> 6] = s;
    __syncthreads();
    if (threadIdx.x == 0) spart[blockIdx.x] = ls[0] + ls[1] + ls[2] + ls[3];
}

// ---------------- K2: per-block sum |w - mean| partials ----------------
__global__ __launch_bounds__(256) void wabs_kernel(const float* __restrict__ w,
                                                   const double* __restrict__ spart,
                                                   double* __restrict__ apart) {
    __shared__ double ls[4];
    double sm = spart[threadIdx.x] + spart[threadIdx.x + 256];
    #pragma unroll
    for (int off = 32; off; off >>= 1) sm += __shfl_down(sm, off);
    if ((threadIdx.x & 63) == 0) ls[threadIdx.x >> 6] = sm;
    __syncthreads();
    double mean = (ls[0] + ls[1] + ls[2] + ls[3]) * (1.0 / (double)W_ELEMS);
    __syncthreads();                                // ls reused below
    int tid = blockIdx.x * 256 + threadIdx.x;
    const float4* w4 = (const float4*)w;
    double s = 0.0;
    #pragma unroll
    for (int it = 0; it < 8; it++) {
        float4 v = w4[tid + it * 131072];
        s += fabs((double)v.x - mean) + fabs((double)v.y - mean) +
             fabs((double)v.z - mean) + fabs((double)v.w - mean);
    }
    #pragma unroll
    for (int off = 32; off; off >>= 1) s += __shfl_down(s, off);
    if ((threadIdx.x & 63) == 0) ls[threadIdx.x >> 6] = s;
    __syncthreads();
    if (threadIdx.x == 0) apart[blockIdx.x] = ls[0] + ls[1] + ls[2] + ls[3];
}

// ---------------- K3: fused x-quant (blocks 0..4095) + w-quant (4096..8191) ----
// wq layout for direct-to-register B loads in the GEMM:
//   wq[(o>>5)][k>>4][o&31][16B]  -> byte addr = (o>>5)*65536 + (k>>4)*512 + (o&31)*16 + (k&15)
// so a wave reading 32 consecutive o-rows of one 16B k-chunk is one coalesced 1KB load.
__global__ __launch_bounds__(256) void quant_kernel(
    const float* __restrict__ x, const float* __restrict__ w,
    const double* __restrict__ spart, const double* __restrict__ apart,
    int8_t* __restrict__ xq, int8_t* __restrict__ wq,
    float* __restrict__ xscale, float* __restrict__ wsf)
{
    const int t = threadIdx.x;
    if (blockIdx.x < 4096) {
        // ---- per-row absmax int8 quant of x: one wave per row ----
        const int row  = (blockIdx.x << 2) | (t >> 6);
        const int lane = t & 63;
        const float4* xr = (const float4*)(x + (size_t)row * K_DIM);
        float4 v[8];
        #pragma unroll
        for (int i = 0; i < 8; i++) v[i] = xr[lane + (i << 6)];
        float m = 0.0f;
        #pragma unroll
        for (int i = 0; i < 8; i++)
            m = fmaxf(m, fmaxf(fmaxf(fabsf(v[i].x), fabsf(v[i].y)),
                               fmaxf(fabsf(v[i].z), fabsf(v[i].w))));
        #pragma unroll
        for (int off = 32; off; off >>= 1) m = fmaxf(m, __shfl_xor(m, off));
        const float scale = fmaxf(m, 1e-5f);
        if (lane == 0) xscale[row] = scale;
        int* outp = (int*)(xq + (size_t)row * K_DIM);
        #pragma unroll
        for (int i = 0; i < 8; i++) {
            int p = qclamp(v[i].x / scale * 127.0f, -128, 127)
                  | (qclamp(v[i].y / scale * 127.0f, -128, 127) << 8)
                  | (qclamp(v[i].z / scale * 127.0f, -128, 127) << 16)
                  | (qclamp(v[i].w / scale * 127.0f, -128, 127) << 24);
            outp[lane + (i << 6)] = p;
        }
    } else {
        // ---- ternary w-quant into the chunked layout ----
        __shared__ double ls0[4], ls1[4];
        double s0 = spart[t] + spart[t + 256];
        double s1 = apart[t] + apart[t + 256];
        #pragma unroll
        for (int off = 32; off; off >>= 1) {
            s0 += __shfl_down(s0, off);
            s1 += __shfl_down(s1, off);
        }
        if ((t & 63) == 0) { ls0[t >> 6] = s0; ls1[t >> 6] = s1; }
        __syncthreads();
        float mean  = (float)((ls0[0] + ls0[1] + ls0[2] + ls0[3]) * (1.0 / (double)W_ELEMS));
        float scale = (float)fmax((ls1[0] + ls1[1] + ls1[2] + ls1[3]) * (1.0 / (double)W_ELEMS), 1e-5);
        int i = (blockIdx.x - 4096) * 256 + t;      // one float4 per thread, exact cover
        float4 v = ((const float4*)w)[i];
        int p = qclamp((v.x - mean) / scale, -1, 1)
              | (qclamp((v.y - mean) / scale, -1, 1) << 8)
              | (qclamp((v.z - mean) / scale, -1, 1) << 16)
              | (qclamp((v.w - mean) / scale, -1, 1) << 24);
        const int o  = i >> 9;                      // 512 float4 per weight row
        const int kw = i & 511;                     // float4 index within the row
        // word index in chunked layout: (o>>5)*16384 + (kw>>2)*128 + (o&31)*4 + (kw&3)
        ((int*)wq)[((o >> 5) << 14) + ((kw >> 2) << 7) + ((o & 31) << 2) + (kw & 3)] = p;
        if (i == 0) wsf[0] = scale * (1.0f / 127.0f);   // dequant factor for gemm
    }
}

// ---------------- int8 GEMM: 256x256 tile, BK=128, 8 waves, A-LDS + B-direct ----
// Round-4 post-mortem: wall = LDS pipe (192 b128 reads + staging writes ~ 2800
// cyc/CU/tile) serialized against MFMA (1306 cyc/SIMD), not barrier overhead.
// Fix: B never touches LDS. wq's chunked layout makes each B-fragment one
// coalesced 1KB global load (L2-resident 4MB) into registers, double-buffered
// across tiles. A stays in LDS (reused 4x across waves) with the rounds-1/2
// PROVEN-0-conflict layout: [2 buf][2 khalf][256 rows][64B], slot = c^((r>>1)&3)
// (row bit 0 enters the bank index; round-4's [256][128] dropped it -> +4cyc/read).
// One vmcnt(0)+lgkm(0)+barrier per K-tile; all loads issued ~1300 cyc earlier.
__global__ __launch_bounds__(512, 2) void gemm_i8_kernel(
    const int8_t* __restrict__ xq, const int8_t* __restrict__ wq,
    const float* __restrict__ xscale, const float* __restrict__ wsf,
    float* __restrict__ out)
{
    __shared__ __align__(16) int8_t lsA[2][32768];   // [buf][kh*16384 + row*64 + slot*16]

    const int tid  = threadIdx.x;
    const int lane = tid & 63;
    const int wv   = tid >> 6;

    // bijective XCD swizzle: 512 wgs, 64/XCD; XCD x owns bm in [8x,8x+8), bn fastest
    const int flat = blockIdx.x;
    const int nf   = ((flat & 7) << 6) | (flat >> 3);
    const int bm   = nf >> 3;                        // 0..63
    const int bn   = nf & 7;                         // 0..7

    // ---- A staging: thread t covers (row = t>>2 in 0..127, slot = t&3) per khalf
    // data chunk at slot s of row r is c = s ^ ((r>>1)&3); rows +128 share the xor
    const int sChunkA = (((tid & 3) ^ ((tid >> 3) & 3)) << 4);
    const int8_t* gAb = xq + (size_t)(bm * 256 + (tid >> 2)) * K_DIM + sChunkA;

    #define STAGE_A(NB, K0)                                                    \
        do {                                                                   \
            async_load16(gAb + (K0),                      lsA[NB] + tid * 16); \
            async_load16(gAb + (K0) + (size_t)128 * K_DIM,                     \
                         lsA[NB] + 8192 + tid * 16);                           \
            async_load16(gAb + (K0) + 64,                 lsA[NB] + 16384 + tid * 16); \
            async_load16(gAb + (K0) + 64 + (size_t)128 * K_DIM,                \
                         lsA[NB] + 16384 + 8192 + tid * 16);                   \
        } while (0)

    // ---- per-wave addressing (32x32x32: row = lane&31, k-chunk = lane>>5) ----
    const int wm  = (wv >> 2) << 7;                  // 0 / 128
    const int l31 = lane & 31;
    const int hi  = lane >> 5;
    const int rx  = (l31 >> 1) & 3;                  // = (row>>1)&3 for all our rows

    int abase[4];
    #pragma unroll
    for (int mi = 0; mi < 4; mi++) abase[mi] = (wm + mi * 32 + l31) << 6;
    int kslot[4];
    #pragma unroll
    for (int ks = 0; ks < 4; ks++)
        kslot[ks] = ((ks >> 1) << 14) + (((((ks & 1) << 1) | hi) ^ rx) << 4);

    // B direct-from-global: wave covers output cols wn..wn+63 = rowblks rb0, rb0+1
    const int rb0 = bn * 8 + (wv & 3) * 2;
    const int8_t* gB0 = wq + ((size_t)rb0 << 16) + (hi << 9) + (l31 << 4);
    const int8_t* gB1 = gB0 + 65536;

    v4i bfA[2][4], bfB[2][4];                        // [nj][ks], double-buffered
    #define LOADB(DST, T)                                                      \
        do {                                                                   \
            _Pragma("unroll")                                                  \
            for (int ks_ = 0; ks_ < 4; ks_++) {                                \
                DST[0][ks_] = *(const v4i*)(gB0 + (T) * 4096 + ks_ * 1024);    \
                DST[1][ks_] = *(const v4i*)(gB1 + (T) * 4096 + ks_ * 1024);    \
            }                                                                  \
        } while (0)

    v16i acc[4][2] = {};

    #define TILE(CUR, NXT, T, CB, NB)                                          \
        do {                                                                   \
            if ((T) < 15) { STAGE_A(NB, ((T) + 1) << 7); LOADB(NXT, (T) + 1); }\
            const int8_t* pA_ = lsA[CB];                                       \
            __builtin_amdgcn_s_setprio(1);                                     \
            _Pragma("unroll")                                                  \
            for (int ks_ = 0; ks_ < 4; ks_++) {                                \
                v4i af[4];                                                     \
                _Pragma("unroll")                                              \
                for (int mi_ = 0; mi_ < 4; mi_++)                              \
                    af[mi_] = *(const v4i*)(pA_ + abase[mi_] + kslot[ks_]);    \
                _Pragma("unroll")                                              \
                for (int mi_ = 0; mi_ < 4; mi_++)                              \
                    _Pragma("unroll")                                          \
                    for (int nj_ = 0; nj_ < 2; nj_++)                          \
                        acc[mi_][nj_] = __builtin_amdgcn_mfma_i32_32x32x32_i8( \
                            af[mi_], CUR[nj_][ks_], acc[mi_][nj_], 0, 0, 0);   \
            }                                                                  \
            __builtin_amdgcn_s_setprio(0);                                     \
            asm volatile("s_waitcnt vmcnt(0) lgkmcnt(0)" ::: "memory");        \
            __builtin_amdgcn_s_barrier();                                      \
        } while (0)

    // prologue: A(0) -> LDS buf0, B(0) -> bfA
    STAGE_A(0, 0);
    LOADB(bfA, 0);
    asm volatile("s_waitcnt vmcnt(0)" ::: "memory");
    __builtin_amdgcn_s_barrier();

    for (int tt = 0; tt < 16; tt += 2) {
        TILE(bfA, bfB, tt,     0, 1);
        TILE(bfB, bfA, tt + 1, 1, 0);
    }
    #undef TILE
    #undef LOADB
    #undef STAGE_A

    // epilogue: dequant. 32x32 C/D: col = lane&31, row = (reg&3) + 8*(reg>>2) + 4*(lane>>5)
    const float f127 = wsf[0];
    const int wn = (wv & 3) << 6;
    #pragma unroll
    for (int mi = 0; mi < 4; mi++) {
        #pragma unroll
        for (int r = 0; r < 16; r++) {
            const int rowl = (r & 3) + ((r >> 2) << 3) + (hi << 2);
            const int mg = bm * 256 + wm + mi * 32 + rowl;
            const float fs = f127 * xscale[mg];
            float* orow = out + (size_t)mg * N_DIM + bn * 256 + wn + l31;
            #pragma unroll
            for (int nj = 0; nj < 2; nj++)
                orow[nj * 32] = fs * (float)acc[mi][nj][r];
        }
    }
}

extern "C" void kernel_launch(void* const* d_in, const int* in_sizes, int n_in,
                              void* d_out, int out_size, void* d_ws, size_t ws_size,
                              hipStream_t stream) {
    const float* x = (const float*)d_in[0];
    const float* w = (const float*)d_in[1];
    float* out = (float*)d_out;

    char* ws = (char*)d_ws;
    double* spart  = (double*)ws;                    // 4 KB (512 doubles)
    double* apart  = (double*)(ws + 4096);           // 4 KB
    float*  wsf    = (float*)(ws + 8192);            // 4 B
    float*  xscale = (float*)(ws + 12288);           // 64 KB
    int8_t* xq     = (int8_t*)(ws + 12288 + 65536);  // 32 MB
    int8_t* wq     = xq + (size_t)M_TOT * K_DIM;     // 4 MB (chunked layout)

    wsum_kernel <<<512, 256, 0, stream>>>(w, spart);
    wabs_kernel <<<512, 256, 0, stream>>>(w, spart, apart);
    quant_kernel<<<8192, 256, 0, stream>>>(x, w, spart, apart, xq, wq, xscale, wsf);
    gemm_i8_kernel<<<512, 512, 0, stream>>>(xq, wq, xscale, wsf, out);
}

// Round 6
// 308.831 us; speedup vs baseline: 1.0323x; 1.0323x over previous
//
#include <hip/hip_runtime.h>
#include <stdint.h>

#define M_TOT 16384      // B*S = 4*4096
#define K_DIM 2048
#define N_DIM 2048
#define W_ELEMS (N_DIM * K_DIM)   // 4194304

typedef int v4i  __attribute__((ext_vector_type(4)));

// ---------------- async global -> LDS, 16B per lane ----------------
__device__ __forceinline__ void async_load16(const void* gptr, void* lptr) {
    __builtin_amdgcn_global_load_lds(
        (__attribute__((address_space(1))) void*)(uintptr_t)gptr,
        (__attribute__((address_space(3))) void*)(uint32_t)(uintptr_t)lptr,
        16, 0, 0);
}

__device__ __forceinline__ int qclamp(float v, int lo, int hi) {
    int q = (int)rintf(v);
    q = q > hi ? hi : (q < lo ? lo : q);
    return q & 255;
}

// ---------------- K1: per-block weight sum partials ----------------
__global__ __launch_bounds__(256) void wsum_kernel(const float* __restrict__ w,
                                                   double* __restrict__ spart) {
    int tid = blockIdx.x * 256 + threadIdx.x;
    const float4* w4 = (const float4*)w;
    double s = 0.0;
    #pragma unroll
    for (int it = 0; it < 8; it++) {               // 512*256*8 float4 = W_ELEMS/4 exact
        float4 v = w4[tid + it * 131072];
        s += (double)v.x + (double)v.y + (double)v.z + (double)v.w;
    }
    #pragma unroll
    for (int off = 32; off; off >>= 1) s += __shfl_down(s, off);
    __shared__ double ls[4];
    if ((threadIdx.x & 63) == 0) ls[threadIdx.x >> 6] = s;
    __syncthreads();
    if (threadIdx.x == 0) spart[blockIdx.x] = ls[0] + ls[1] + ls[2] + ls[3];
}

// ---------------- K2: per-block sum |w - mean| partials ----------------
__global__ __launch_bounds__(256) void wabs_kernel(const float* __restrict__ w,
                                                   const double* __restrict__ spart,
                                                   double* __restrict__ apart) {
    __shared__ double ls[4];
    double sm = spart[threadIdx.x] + spart[threadIdx.x + 256];
    #pragma unroll
    for (int off = 32; off; off >>= 1) sm += __shfl_down(sm, off);
    if ((threadIdx.x & 63) == 0) ls[threadIdx.x >> 6] = sm;
    __syncthreads();
    double mean = (ls[0] + ls[1] + ls[2] + ls[3]) * (1.0 / (double)W_ELEMS);
    __syncthreads();                                // ls reused below
    int tid = blockIdx.x * 256 + threadIdx.x;
    const float4* w4 = (const float4*)w;
    double s = 0.0;
    #pragma unroll
    for (int it = 0; it < 8; it++) {
        float4 v = w4[tid + it * 131072];
        s += fabs((double)v.x - mean) + fabs((double)v.y - mean) +
             fabs((double)v.z - mean) + fabs((double)v.w - mean);
    }
    #pragma unroll
    for (int off = 32; off; off >>= 1) s += __shfl_down(s, off);
    if ((threadIdx.x & 63) == 0) ls[threadIdx.x >> 6] = s;
    __syncthreads();
    if (threadIdx.x == 0) apart[blockIdx.x] = ls[0] + ls[1] + ls[2] + ls[3];
}

// ---------------- K3: fused x-quant (blocks 0..4095) + w-quant (4096..8191) ----
__global__ __launch_bounds__(256) void quant_kernel(
    const float* __restrict__ x, const float* __restrict__ w,
    const double* __restrict__ spart, const double* __restrict__ apart,
    int8_t* __restrict__ xq, int8_t* __restrict__ wq,
    float* __restrict__ xscale, float* __restrict__ wsf)
{
    const int t = threadIdx.x;
    if (blockIdx.x < 4096) {
        // ---- per-row absmax int8 quant of x: one wave per row ----
        const int row  = (blockIdx.x << 2) | (t >> 6);
        const int lane = t & 63;
        const float4* xr = (const float4*)(x + (size_t)row * K_DIM);
        float4 v[8];
        #pragma unroll
        for (int i = 0; i < 8; i++) v[i] = xr[lane + (i << 6)];
        float m = 0.0f;
        #pragma unroll
        for (int i = 0; i < 8; i++)
            m = fmaxf(m, fmaxf(fmaxf(fabsf(v[i].x), fabsf(v[i].y)),
                               fmaxf(fabsf(v[i].z), fabsf(v[i].w))));
        #pragma unroll
        for (int off = 32; off; off >>= 1) m = fmaxf(m, __shfl_xor(m, off));
        const float scale = fmaxf(m, 1e-5f);
        if (lane == 0) xscale[row] = scale;
        int* outp = (int*)(xq + (size_t)row * K_DIM);
        #pragma unroll
        for (int i = 0; i < 8; i++) {
            int p = qclamp(v[i].x / scale * 127.0f, -128, 127)
                  | (qclamp(v[i].y / scale * 127.0f, -128, 127) << 8)
                  | (qclamp(v[i].z / scale * 127.0f, -128, 127) << 16)
                  | (qclamp(v[i].w / scale * 127.0f, -128, 127) << 24);
            outp[lane + (i << 6)] = p;
        }
    } else {
        // ---- ternary w-quant (plain row-major; B is LDS-staged in the GEMM) ----
        __shared__ double ls0[4], ls1[4];
        double s0 = spart[t] + spart[t + 256];
        double s1 = apart[t] + apart[t + 256];
        #pragma unroll
        for (int off = 32; off; off >>= 1) {
            s0 += __shfl_down(s0, off);
            s1 += __shfl_down(s1, off);
        }
        if ((t & 63) == 0) { ls0[t >> 6] = s0; ls1[t >> 6] = s1; }
        __syncthreads();
        float mean  = (float)((ls0[0] + ls0[1] + ls0[2] + ls0[3]) * (1.0 / (double)W_ELEMS));
        float scale = (float)fmax((ls1[0] + ls1[1] + ls1[2] + ls1[3]) * (1.0 / (double)W_ELEMS), 1e-5);
        int i = (blockIdx.x - 4096) * 256 + t;      // one float4 per thread, exact cover
        float4 v = ((const float4*)w)[i];
        int p = qclamp((v.x - mean) / scale, -1, 1)
              | (qclamp((v.y - mean) / scale, -1, 1) << 8)
              | (qclamp((v.z - mean) / scale, -1, 1) << 16)
              | (qclamp((v.w - mean) / scale, -1, 1) << 24);
        ((int*)wq)[i] = p;
        if (i == 0) wsf[0] = scale * (1.0f / 127.0f);   // dequant factor for gemm
    }
}

// ---------------- int8 GEMM: 256x256 tile, BK=64, 8 waves, one barrier/tile ----
// Empirical rules from rounds 1-5 (all measured on this problem):
//   * 16-row fragment reads (16x16x64, row=lane&15) with slot = c^((r>>1)&3):
//     0 bank conflicts (R1/R2). 32-row fragments (32x32): +4 cyc/read in two
//     different swizzles (R4/R5). -> use 16x16x64.
//   * One barrier per K-tile amortizes the ~600cyc barrier/drain overhead
//     (R4) -> keep, but at BK=64 so LDS = 64KiB -> 2 blocks/CU, giving two
//     independent barrier domains that cover each other's drains (R2's idea,
//     which failed there only because its phases were too small: 16 MFMA
//     (~82cyc) per ~600cyc overhead; here 256 MFMA (~1300cyc) per overhead).
// Per-CU floors: matrix ~35us, LDS pipe ~38us -> balanced; target 50-60us.
//   LDS per op per buf: [256 rows][64B], chunk-slot swizzle s = c^((r>>1)&3)
//   applied on the global SOURCE (linear DMA dest, both-sides-or-neither).
//   Per tile: STAGE(t+1 -> buf^1) first (4 loads/thread, ~1300cyc before the
//   drain, >> L2 latency), 12 ds_read_b128, 32 MFMA, vmcnt(0)+lgkm(0)+barrier.
__global__ __launch_bounds__(512, 2) void gemm_i8_kernel(
    const int8_t* __restrict__ xq, const int8_t* __restrict__ wq,
    const float* __restrict__ xscale, const float* __restrict__ wsf,
    float* __restrict__ out)
{
    __shared__ __align__(16) int8_t lsA[2][16384];   // [buf][row*64 + slot*16]
    __shared__ __align__(16) int8_t lsB[2][16384];

    const int tid  = threadIdx.x;
    const int lane = tid & 63;
    const int wv   = tid >> 6;

    // bijective XCD swizzle: 512 wgs, 64/XCD; XCD x owns bm in [8x,8x+8), bn fastest
    const int flat = blockIdx.x;
    const int nf   = ((flat & 7) << 6) | (flat >> 3);
    const int bm   = nf >> 3;                        // 0..63
    const int bn   = nf & 7;                         // 0..7

    // staging: instr pair covers (row = tid>>2 in 0..127, slot = tid&3) and row+128
    // data chunk stored at slot s of row r is c = s ^ ((r>>1)&3); (r+128) keeps the xor
    const int sChunk = (((tid & 3) ^ ((tid >> 3) & 3)) << 4);
    const int8_t* gAb = xq + (size_t)(bm * 256 + (tid >> 2)) * K_DIM + sChunk;
    const int8_t* gBb = wq + (size_t)(bn * 256 + (tid >> 2)) * K_DIM + sChunk;

    #define STAGE(NB, K0)                                                      \
        do {                                                                   \
            async_load16(gAb + (K0),                       lsA[NB] + tid * 16);\
            async_load16(gAb + (K0) + (size_t)128 * K_DIM, lsA[NB] + 8192 + tid * 16); \
            async_load16(gBb + (K0),                       lsB[NB] + tid * 16);\
            async_load16(gBb + (K0) + (size_t)128 * K_DIM, lsB[NB] + 8192 + tid * 16); \
        } while (0)

    // per-wave fragments (16x16x64: row = lane&15, k-chunk = lane>>4), R1/R2-proven
    const int wm = (wv >> 2) << 7;                   // 0 / 128
    const int wn = (wv & 3) << 6;                    // 0 / 64 / 128 / 192
    const int fr = lane & 15;
    const int fc = lane >> 4;                        // 16B k-chunk 0..3
    int aoff[8], boff[4];
    #pragma unroll
    for (int mi = 0; mi < 8; mi++) {
        int ra = wm + mi * 16 + fr;
        aoff[mi] = ra * 64 + ((fc ^ ((ra >> 1) & 3)) << 4);
    }
    #pragma unroll
    for (int nj = 0; nj < 4; nj++) {
        int rb = wn + nj * 16 + fr;
        boff[nj] = rb * 64 + ((fc ^ ((rb >> 1) & 3)) << 4);
    }

    v4i acc[8][4] = {};

    #define TILE(CB, T)                                                        \
        do {                                                                   \
            if ((T) < 31) STAGE((CB) ^ 1, ((T) + 1) << 6);                     \
            v4i af[8], bf[4];                                                  \
            _Pragma("unroll")                                                  \
            for (int mi_ = 0; mi_ < 8; mi_++)                                  \
                af[mi_] = *(const v4i*)(lsA[CB] + aoff[mi_]);                  \
            _Pragma("unroll")                                                  \
            for (int nj_ = 0; nj_ < 4; nj_++)                                  \
                bf[nj_] = *(const v4i*)(lsB[CB] + boff[nj_]);                  \
            __builtin_amdgcn_s_setprio(1);                                     \
            _Pragma("unroll")                                                  \
            for (int mi_ = 0; mi_ < 8; mi_++)                                  \
                _Pragma("unroll")                                              \
                for (int nj_ = 0; nj_ < 4; nj_++)                              \
                    acc[mi_][nj_] = __builtin_amdgcn_mfma_i32_16x16x64_i8(     \
                        af[mi_], bf[nj_], acc[mi_][nj_], 0, 0, 0);             \
            __builtin_amdgcn_s_setprio(0);                                     \
            asm volatile("s_waitcnt vmcnt(0) lgkmcnt(0)" ::: "memory");        \
            __builtin_amdgcn_s_barrier();                                      \
        } while (0)

    // prologue: tile 0 -> buf0
    STAGE(0, 0);
    asm volatile("s_waitcnt vmcnt(0)" ::: "memory");
    __builtin_amdgcn_s_barrier();

    for (int t = 0; t < 32; t += 2) {
        TILE(0, t);
        TILE(1, t + 1);
    }
    #undef TILE
    #undef STAGE

    // epilogue: dequant. 16x16 C/D: col = lane&15, row = (lane>>4)*4 + reg (R1-proven)
    const float f127 = wsf[0];
    #pragma unroll
    for (int mi = 0; mi < 8; mi++) {
        #pragma unroll
        for (int rg = 0; rg < 4; rg++) {
            const int mg = bm * 256 + wm + mi * 16 + (lane >> 4) * 4 + rg;
            const float fs = f127 * xscale[mg];
            float* orow = out + (size_t)mg * N_DIM + bn * 256 + wn;
            #pragma unroll
            for (int nj = 0; nj < 4; nj++)
                orow[nj * 16 + fr] = fs * (float)acc[mi][nj][rg];
        }
    }
}

extern "C" void kernel_launch(void* const* d_in, const int* in_sizes, int n_in,
                              void* d_out, int out_size, void* d_ws, size_t ws_size,
                              hipStream_t stream) {
    const float* x = (const float*)d_in[0];
    const float* w = (const float*)d_in[1];
    float* out = (float*)d_out;

    char* ws = (char*)d_ws;
    double* spart  = (double*)ws;                    // 4 KB (512 doubles)
    double* apart  = (double*)(ws + 4096);           // 4 KB
    float*  wsf    = (float*)(ws + 8192);            // 4 B
    float*  xscale = (float*)(ws + 12288);           // 64 KB
    int8_t* xq     = (int8_t*)(ws + 12288 + 65536);  // 32 MB
    int8_t* wq     = xq + (size_t)M_TOT * K_DIM;     // 4 MB (row-major)

    wsum_kernel <<<512, 256, 0, stream>>>(w, spart);
    wabs_kernel <<<512, 256, 0, stream>>>(w, spart, apart);
    quant_kernel<<<8192, 256, 0, stream>>>(x, w, spart, apart, xq, wq, xscale, wsf);
    gemm_i8_kernel<<<512, 512, 0, stream>>>(xq, wq, xscale, wsf, out);
}

// Round 7
// 307.868 us; speedup vs baseline: 1.0355x; 1.0031x over previous
//
#include <hip/hip_runtime.h>
#include <stdint.h>

#define M_TOT 16384      // B*S = 4*4096
#define K_DIM 2048
#define N_DIM 2048
#define W_ELEMS (N_DIM * K_DIM)   // 4194304

typedef int v4i  __attribute__((ext_vector_type(4)));

// ---------------- async global -> LDS, 16B per lane ----------------
__device__ __forceinline__ void async_load16(const void* gptr, void* lptr) {
    __builtin_amdgcn_global_load_lds(
        (__attribute__((address_space(1))) void*)(uintptr_t)gptr,
        (__attribute__((address_space(3))) void*)(uint32_t)(uintptr_t)lptr,
        16, 0, 0);
}

__device__ __forceinline__ int qclamp(float v, int lo, int hi) {
    int q = (int)rintf(v);
    q = q > hi ? hi : (q < lo ? lo : q);
    return q & 255;
}

// ---------------- K1: per-block weight sum partials ----------------
__global__ __launch_bounds__(256) void wsum_kernel(const float* __restrict__ w,
                                                   double* __restrict__ spart) {
    int tid = blockIdx.x * 256 + threadIdx.x;
    const float4* w4 = (const float4*)w;
    double s = 0.0;
    #pragma unroll
    for (int it = 0; it < 8; it++) {               // 512*256*8 float4 = W_ELEMS/4 exact
        float4 v = w4[tid + it * 131072];
        s += (double)v.x + (double)v.y + (double)v.z + (double)v.w;
    }
    #pragma unroll
    for (int off = 32; off; off >>= 1) s += __shfl_down(s, off);
    __shared__ double ls[4];
    if ((threadIdx.x & 63) == 0) ls[threadIdx.x >> 6] = s;
    __syncthreads();
    if (threadIdx.x == 0) spart[blockIdx.x] = ls[0] + ls[1] + ls[2] + ls[3];
}

// ---------------- K2: per-block sum |w - mean| partials ----------------
__global__ __launch_bounds__(256) void wabs_kernel(const float* __restrict__ w,
                                                   const double* __restrict__ spart,
                                                   double* __restrict__ apart) {
    __shared__ double ls[4];
    double sm = spart[threadIdx.x] + spart[threadIdx.x + 256];
    #pragma unroll
    for (int off = 32; off; off >>= 1) sm += __shfl_down(sm, off);
    if ((threadIdx.x & 63) == 0) ls[threadIdx.x >> 6] = sm;
    __syncthreads();
    double mean = (ls[0] + ls[1] + ls[2] + ls[3]) * (1.0 / (double)W_ELEMS);
    __syncthreads();                                // ls reused below
    int tid = blockIdx.x * 256 + threadIdx.x;
    const float4* w4 = (const float4*)w;
    double s = 0.0;
    #pragma unroll
    for (int it = 0; it < 8; it++) {
        float4 v = w4[tid + it * 131072];
        s += fabs((double)v.x - mean) + fabs((double)v.y - mean) +
             fabs((double)v.z - mean) + fabs((double)v.w - mean);
    }
    #pragma unroll
    for (int off = 32; off; off >>= 1) s += __shfl_down(s, off);
    if ((threadIdx.x & 63) == 0) ls[threadIdx.x >> 6] = s;
    __syncthreads();
    if (threadIdx.x == 0) apart[blockIdx.x] = ls[0] + ls[1] + ls[2] + ls[3];
}

// ---------------- K3: fused x-quant (blocks 0..4095) + w-quant (4096..8191) ----
__global__ __launch_bounds__(256) void quant_kernel(
    const float* __restrict__ x, const float* __restrict__ w,
    const double* __restrict__ spart, const double* __restrict__ apart,
    int8_t* __restrict__ xq, int8_t* __restrict__ wq,
    float* __restrict__ xscale, float* __restrict__ wsf)
{
    const int t = threadIdx.x;
    if (blockIdx.x < 4096) {
        // ---- per-row absmax int8 quant of x: one wave per row ----
        const int row  = (blockIdx.x << 2) | (t >> 6);
        const int lane = t & 63;
        const float4* xr = (const float4*)(x + (size_t)row * K_DIM);
        float4 v[8];
        #pragma unroll
        for (int i = 0; i < 8; i++) v[i] = xr[lane + (i << 6)];
        float m = 0.0f;
        #pragma unroll
        for (int i = 0; i < 8; i++)
            m = fmaxf(m, fmaxf(fmaxf(fabsf(v[i].x), fabsf(v[i].y)),
                               fmaxf(fabsf(v[i].z), fabsf(v[i].w))));
        #pragma unroll
        for (int off = 32; off; off >>= 1) m = fmaxf(m, __shfl_xor(m, off));
        const float scale = fmaxf(m, 1e-5f);
        if (lane == 0) xscale[row] = scale;
        const float rs = 127.0f / scale;            // one divide, 32 multiplies
        int* outp = (int*)(xq + (size_t)row * K_DIM);
        #pragma unroll
        for (int i = 0; i < 8; i++) {
            int p = qclamp(v[i].x * rs, -128, 127)
                  | (qclamp(v[i].y * rs, -128, 127) << 8)
                  | (qclamp(v[i].z * rs, -128, 127) << 16)
                  | (qclamp(v[i].w * rs, -128, 127) << 24);
            outp[lane + (i << 6)] = p;
        }
    } else {
        // ---- ternary w-quant (plain row-major; B is LDS-staged in the GEMM) ----
        __shared__ double ls0[4], ls1[4];
        double s0 = spart[t] + spart[t + 256];
        double s1 = apart[t] + apart[t + 256];
        #pragma unroll
        for (int off = 32; off; off >>= 1) {
            s0 += __shfl_down(s0, off);
            s1 += __shfl_down(s1, off);
        }
        if ((t & 63) == 0) { ls0[t >> 6] = s0; ls1[t >> 6] = s1; }
        __syncthreads();
        float mean  = (float)((ls0[0] + ls0[1] + ls0[2] + ls0[3]) * (1.0 / (double)W_ELEMS));
        float scale = (float)fmax((ls1[0] + ls1[1] + ls1[2] + ls1[3]) * (1.0 / (double)W_ELEMS), 1e-5);
        const float ri = 1.0f / scale;
        int i = (blockIdx.x - 4096) * 256 + t;      // one float4 per thread, exact cover
        float4 v = ((const float4*)w)[i];
        int p = qclamp((v.x - mean) * ri, -1, 1)
              | (qclamp((v.y - mean) * ri, -1, 1) << 8)
              | (qclamp((v.z - mean) * ri, -1, 1) << 16)
              | (qclamp((v.w - mean) * ri, -1, 1) << 24);
        ((int*)wq)[i] = p;
        if (i == 0) wsf[0] = scale * (1.0f / 127.0f);   // dequant factor for gemm
    }
}

// ---------------- int8 GEMM: 256x256 tile, BK=64, 8 waves, 3-deep pipeline ----
// R1-R6 post-mortem: every structure so far paired its barrier with a stalling
// wait (R6: vmcnt(0) ~1 tile after issue < HBM latency; R1: counted vmcnt but
// 8 barriers/tile). Calibration vs the verified bf16 m201 template (same 16.4
// cyc/MFMA, same 8 waves/CU, 62% util) says ~1700 cyc/tile is recoverable.
// This round: ONE barrier per tile AND a never-stalling counted wait.
//   3 LDS buffers (96 KiB): tile t computes buf[t%3], stages tile t+2 into
//   buf[(t+2)%3], then waits vmcnt(4) -- draining tile t+1's 4 loads, which
//   were issued a full 2 tiles (~2800 cyc) earlier >> 900 cyc HBM latency.
//   Buffer-overwrite safety: staging into buf b at tile t starts after the
//   barrier of tile t-1, by which point all waves' ds_reads of b (tile t-3)
//   have long retired into registers.
//   Layout (R1/R2/R6-proven, 0 conflicts): per op per buf [256 rows][64B],
//   chunk-slot swizzle s = c ^ ((r>>1)&3) on the global SOURCE; 16x16x64
//   fragments (row = lane&15 -- 16-row reads are the measured-conflict-free
//   pattern; 32-row fragments cost +4 cyc/read in two swizzles, R4/R5).
__global__ __launch_bounds__(512, 2) void gemm_i8_kernel(
    const int8_t* __restrict__ xq, const int8_t* __restrict__ wq,
    const float* __restrict__ xscale, const float* __restrict__ wsf,
    float* __restrict__ out)
{
    __shared__ __align__(16) int8_t lsA[3][16384];   // [buf][row*64 + slot*16]
    __shared__ __align__(16) int8_t lsB[3][16384];

    const int tid  = threadIdx.x;
    const int lane = tid & 63;
    const int wv   = tid >> 6;

    // bijective XCD swizzle: 512 wgs, 64/XCD; XCD x owns bm in [8x,8x+8), bn fastest
    const int flat = blockIdx.x;
    const int nf   = ((flat & 7) << 6) | (flat >> 3);
    const int bm   = nf >> 3;                        // 0..63
    const int bn   = nf & 7;                         // 0..7

    // staging: instr pair covers (row = tid>>2 in 0..127, slot = tid&3) and row+128
    // data chunk stored at slot s of row r is c = s ^ ((r>>1)&3); (r+128) keeps the xor
    const int sChunk = (((tid & 3) ^ ((tid >> 3) & 3)) << 4);
    const int8_t* gAb = xq + (size_t)(bm * 256 + (tid >> 2)) * K_DIM + sChunk;
    const int8_t* gBb = wq + (size_t)(bn * 256 + (tid >> 2)) * K_DIM + sChunk;

    #define STAGE(NB, T)                                                       \
        do {                                                                   \
            async_load16(gAb + ((T) << 6),                       lsA[NB] + tid * 16); \
            async_load16(gAb + ((T) << 6) + (size_t)128 * K_DIM, lsA[NB] + 8192 + tid * 16); \
            async_load16(gBb + ((T) << 6),                       lsB[NB] + tid * 16); \
            async_load16(gBb + ((T) << 6) + (size_t)128 * K_DIM, lsB[NB] + 8192 + tid * 16); \
        } while (0)

    // per-wave fragments (16x16x64: row = lane&15, k-chunk = lane>>4)
    const int wm = (wv >> 2) << 7;                   // 0 / 128
    const int wn = (wv & 3) << 6;                    // 0 / 64 / 128 / 192
    const int fr = lane & 15;
    const int fc = lane >> 4;                        // 16B k-chunk 0..3
    int aoff[8], boff[4];
    #pragma unroll
    for (int mi = 0; mi < 8; mi++) {
        int ra = wm + mi * 16 + fr;
        aoff[mi] = ra * 64 + ((fc ^ ((ra >> 1) & 3)) << 4);
    }
    #pragma unroll
    for (int nj = 0; nj < 4; nj++) {
        int rb = wn + nj * 16 + fr;
        boff[nj] = rb * 64 + ((fc ^ ((rb >> 1) & 3)) << 4);
    }

    v4i acc[8][4] = {};

    #define COMPUTE(CB)                                                        \
        do {                                                                   \
            v4i af[8], bf[4];                                                  \
            _Pragma("unroll")                                                  \
            for (int mi_ = 0; mi_ < 8; mi_++)                                  \
                af[mi_] = *(const v4i*)(lsA[CB] + aoff[mi_]);                  \
            _Pragma("unroll")                                                  \
            for (int nj_ = 0; nj_ < 4; nj_++)                                  \
                bf[nj_] = *(const v4i*)(lsB[CB] + boff[nj_]);                  \
            __builtin_amdgcn_s_setprio(1);                                     \
            _Pragma("unroll")                                                  \
            for (int mi_ = 0; mi_ < 8; mi_++)                                  \
                _Pragma("unroll")                                              \
                for (int nj_ = 0; nj_ < 4; nj_++)                              \
                    acc[mi_][nj_] = __builtin_amdgcn_mfma_i32_16x16x64_i8(     \
                        af[mi_], bf[nj_], acc[mi_][nj_], 0, 0, 0);             \
            __builtin_amdgcn_s_setprio(0);                                     \
        } while (0)

    // TILE for t <= 29: stage t+2, compute buf t%3, wait vmcnt(4) (drains t+1's
    // 4 loads, issued 2 tiles earlier), one barrier.
    #define TILE_MID(CB, NB, T)                                                \
        do {                                                                   \
            STAGE(NB, (T) + 2);                                                \
            COMPUTE(CB);                                                       \
            asm volatile("s_waitcnt vmcnt(4)" ::: "memory");                   \
            __builtin_amdgcn_s_barrier();                                      \
        } while (0)

    // prologue: tiles 0,1 in flight; wait tile 0 (leave tile 1's 4 outstanding)
    STAGE(0, 0);
    STAGE(1, 1);
    asm volatile("s_waitcnt vmcnt(4)" ::: "memory");
    __builtin_amdgcn_s_barrier();

    for (int tt = 0; tt < 30; tt += 3) {
        TILE_MID(0, 2, tt);
        TILE_MID(1, 0, tt + 1);
        TILE_MID(2, 1, tt + 2);
    }
    // t = 30: nothing left to stage; drain tile 31 (issued at t=29, ~1 tile ago)
    COMPUTE(0);
    asm volatile("s_waitcnt vmcnt(0)" ::: "memory");
    __builtin_amdgcn_s_barrier();
    // t = 31: last tile, no wait, no barrier
    COMPUTE(1);

    #undef TILE_MID
    #undef COMPUTE
    #undef STAGE

    // epilogue: dequant. 16x16 C/D: col = lane&15, row = (lane>>4)*4 + reg
    const float f127 = wsf[0];
    #pragma unroll
    for (int mi = 0; mi < 8; mi++) {
        #pragma unroll
        for (int rg = 0; rg < 4; rg++) {
            const int mg = bm * 256 + wm + mi * 16 + (lane >> 4) * 4 + rg;
            const float fs = f127 * xscale[mg];
            float* orow = out + (size_t)mg * N_DIM + bn * 256 + wn;
            #pragma unroll
            for (int nj = 0; nj < 4; nj++)
                orow[nj * 16 + fr] = fs * (float)acc[mi][nj][rg];
        }
    }
}

extern "C" void kernel_launch(void* const* d_in, const int* in_sizes, int n_in,
                              void* d_out, int out_size, void* d_ws, size_t ws_size,
                              hipStream_t stream) {
    const float* x = (const float*)d_in[0];
    const float* w = (const float*)d_in[1];
    float* out = (float*)d_out;

    char* ws = (char*)d_ws;
    double* spart  = (double*)ws;                    // 4 KB (512 doubles)
    double* apart  = (double*)(ws + 4096);           // 4 KB
    float*  wsf    = (float*)(ws + 8192);            // 4 B
    float*  xscale = (float*)(ws + 12288);           // 64 KB
    int8_t* xq     = (int8_t*)(ws + 12288 + 65536);  // 32 MB
    int8_t* wq     = xq + (size_t)M_TOT * K_DIM;     // 4 MB (row-major)

    wsum_kernel <<<512, 256, 0, stream>>>(w, spart);
    wabs_kernel <<<512, 256, 0, stream>>>(w, spart, apart);
    quant_kernel<<<8192, 256, 0, stream>>>(x, w, spart, apart, xq, wq, xscale, wsf);
    gemm_i8_kernel<<<512, 512, 0, stream>>>(xq, wq, xscale, wsf, out);
}